// Round 1
// 880.533 us; speedup vs baseline: 1.1703x; 1.1703x over previous
//
#include <hip/hip_runtime.h>
#include <hip/hip_bf16.h>

#define N_NODES 100000
#define N_EDGES 3200000
#define HID 16
#define MAXDEG 128   // per-node entry clamp (realized max deg ~110; never fires)
#define NB 256       // node buckets for the 2-phase build
#define NPB 391      // nodes per bucket: 256*391 = 100096 >= 100000
#define PCAP 28672   // per-bucket pair capacity (mean 25024, sigma ~158 -> +23 sigma)
#define FDEPTH 48    // LDS FIFO depth per bucket in k_split
#define LCAP 26624   // LDS sort buffer entries in k_bsort (104 KB)

static constexpr int BLK = 256;

__device__ __forceinline__ float frelu(float x) { return fmaxf(x, 0.f); }
__device__ __forceinline__ float bf2f(unsigned short u) {
  return __uint_as_float(((unsigned int)u) << 16);
}

// 16 bf16 (32 B) viewed as two float4 for vector load/store
union E16 {
  float4 f4[2];
  __hip_bfloat16 h[16];
};

// ---------------------------------------------------------------------------
// K0: norm = max |edges_init|
// ---------------------------------------------------------------------------
__global__ __launch_bounds__(256) void k_norm(const float* __restrict__ edges,
                                              unsigned int* __restrict__ normbits) {
  float m = 0.f;
  for (int i = blockIdx.x * blockDim.x + threadIdx.x; i < N_EDGES;
       i += gridDim.x * blockDim.x)
    m = fmaxf(m, fabsf(edges[i]));
#pragma unroll
  for (int off = 32; off > 0; off >>= 1)
    m = fmaxf(m, __shfl_down(m, off, 64));
  __shared__ float smax[BLK / 64];
  if ((threadIdx.x & 63) == 0) smax[threadIdx.x >> 6] = m;
  __syncthreads();
  if (threadIdx.x == 0) {
    float b = smax[0];
#pragma unroll
    for (int w = 1; w < BLK / 64; ++w) b = fmaxf(b, smax[w]);
    atomicMax(normbits, __float_as_uint(b));
  }
}

// ---------------------------------------------------------------------------
// K1a: multisplit edge-sides into NB node-buckets via LDS FIFOs.
// Replaces the old scattered-4B ELL build: every edge-side becomes one LDS
// atomic + LDS store; global traffic is 16-entry (64 B line) flushes with one
// global atomic per flush (~430K line ops instead of 12.8M scattered 4B ops).
// pair = (node_local << 23) | (edge << 1) | side   -- fits 32 bits (9+22+1)
// ---------------------------------------------------------------------------
__global__ __launch_bounds__(1024) void k_split(const int* __restrict__ senders,
                                                const int* __restrict__ receivers,
                                                int* __restrict__ gcnt,
                                                unsigned int* __restrict__ pairs) {
  __shared__ __align__(16) unsigned int fifo[NB][FDEPTH];
  __shared__ int fcnt[NB];
  const int t = threadIdx.x;
  if (t < NB) fcnt[t] = 0;
  __syncthreads();
  const int e0 = blockIdx.x * (N_EDGES / 256);
  const int e1 = e0 + (N_EDGES / 256);
  for (int base = e0; base < e1; base += 1024) {
    const int i = base + t;
    if (i < e1) {
      int s = senders[i];
      unsigned int bs = (unsigned int)s / NPB;
      unsigned int us = (((unsigned int)s - bs * NPB) << 23) | ((unsigned int)i << 1);
      int pos = atomicAdd(&fcnt[bs], 1);
      if (pos < FDEPTH) {
        fifo[bs][pos] = us;
      } else {  // overflow (astronomically rare): direct single append
        int gb = atomicAdd(&gcnt[bs], 1);
        if (gb < PCAP) pairs[(size_t)bs * PCAP + gb] = us;
      }
      int r = receivers[i];
      unsigned int br = (unsigned int)r / NPB;
      unsigned int ur = (((unsigned int)r - br * NPB) << 23) | ((unsigned int)i << 1) | 1u;
      pos = atomicAdd(&fcnt[br], 1);
      if (pos < FDEPTH) {
        fifo[br][pos] = ur;
      } else {
        int gb = atomicAdd(&gcnt[br], 1);
        if (gb < PCAP) pairs[(size_t)br * PCAP + gb] = ur;
      }
    }
    __syncthreads();
    const bool last = (base + 1024 >= e1);
    if (t < NB) {  // thread t owns bucket t's FIFO between barriers
      int c = fcnt[t];
      if (c > FDEPTH) c = FDEPTH;
      int nf = last ? c : (c & ~15);  // flush whole 64B lines; drain on last
      if (nf > 0) {
        int gb = atomicAdd(&gcnt[t], nf);
        unsigned int* dst = pairs + (size_t)t * PCAP + gb;
        if ((gb & 3) == 0 && gb + nf <= PCAP) {  // common case: 16B-aligned
          int k = 0;
          for (; k + 4 <= nf; k += 4)
            *(uint4*)(dst + k) = *(const uint4*)(&fifo[t][k]);
          for (; k < nf; ++k) dst[k] = fifo[t][k];
        } else {  // misaligned after a drain/overflow, or capacity edge
          for (int k = 0; k < nf; ++k)
            if (gb + k < PCAP) dst[k] = fifo[t][k];
        }
        int res = c - nf;  // res <= 15 < nf: no overlap in the memmove
        for (int k = 0; k < res; ++k) fifo[t][k] = fifo[t][nf + k];
        fcnt[t] = res;
      } else {
        fcnt[t] = c;
      }
    }
    __syncthreads();
  }
}

// ---------------------------------------------------------------------------
// K1b: per-bucket LDS counting sort -> dense per-bucket CSR (ell, off, deg).
// One block per bucket (256 blocks = 1 per CU). All scatter is LDS-only;
// global writes are fully coalesced. Chunk loop is a safety net (1 chunk in
// practice: bucket total ~25024 +- 158 << LCAP).
// ---------------------------------------------------------------------------
__global__ __launch_bounds__(1024) void k_bsort(const unsigned int* __restrict__ pairs,
                                                const int* __restrict__ gcnt,
                                                int* __restrict__ ell,
                                                int* __restrict__ off,
                                                int* __restrict__ deg) {
  __shared__ unsigned int sorted[LCAP];  // 104 KB
  __shared__ int hist[NPB + 1];
  __shared__ int pref[NPB + 1];
  __shared__ int sc[NPB];
  __shared__ int cur[NPB];
  const int b = blockIdx.x;
  const int t = threadIdx.x;
  const int nt = blockDim.x;
  int nb = gcnt[b];
  if (nb > PCAP) nb = PCAP;
  const unsigned int* P = pairs + (size_t)b * PCAP;
  for (int k = t; k <= NPB; k += nt) hist[k] = 0;
  __syncthreads();
  for (int i = t; i < nb; i += nt) atomicAdd(&hist[P[i] >> 23], 1);
  __syncthreads();
  if (t < NPB) {
    int c = hist[t];
    sc[t] = (c > MAXDEG) ? MAXDEG : c;
  }
  __syncthreads();
  if (t < NPB) hist[t] = sc[t];  // keep clamped counts
  // inclusive Hillis-Steele scan of sc[0..NPB)
  for (int d = 1; d < NPB; d <<= 1) {
    int add = 0;
    if (t < NPB && t >= d) add = sc[t - d];
    __syncthreads();
    if (t < NPB && t >= d) sc[t] += add;
    __syncthreads();
  }
  if (t < NPB) pref[t] = sc[t] - hist[t];  // exclusive prefix
  if (t == 0) pref[NPB] = sc[NPB - 1];
  __syncthreads();
  // per-node CSR offsets and degrees
  const int node0 = b * NPB;
  for (int k = t; k < NPB; k += nt) {
    int n = node0 + k;
    if (n < N_NODES) {
      off[n] = b * PCAP + pref[k];
      deg[n] = hist[k];
    }
  }
  // chunked: scatter into LDS by node, then coalesced writeout
  int nlo = 0;
  while (nlo < NPB) {
    const int base0 = pref[nlo];
    int nhi = nlo;  // uniform across threads (reads shared pref)
    while (nhi < NPB && pref[nhi + 1] - base0 <= LCAP) ++nhi;
    for (int k = nlo + t; k < nhi; k += nt) cur[k] = pref[k] - base0;
    __syncthreads();
    for (int i = t; i < nb; i += nt) {
      unsigned int u = P[i];  // second read: L2-warm
      int nl = u >> 23;
      if (nl >= nlo && nl < nhi) {
        int p = atomicAdd(&cur[nl], 1);
        if (p < pref[nl] - base0 + hist[nl]) sorted[p] = u & 0x7FFFFFu;
      }
    }
    __syncthreads();
    const int csz = pref[nhi] - base0;
    int* dst = ell + (size_t)b * PCAP + base0;
    for (int i = t; i < csz; i += nt) dst[i] = (int)sorted[i];
    __syncthreads();
    nlo = nhi;
  }
}

// ---------------------------------------------------------------------------
// K2: edge encoder (1 -> HID -> HID), writes e (bf16)
// ---------------------------------------------------------------------------
__global__ __launch_bounds__(256) void k_encode(
    const float* __restrict__ edges, const float* __restrict__ w1,
    const float* __restrict__ b1, const float* __restrict__ w2,
    const float* __restrict__ b2, const unsigned int* __restrict__ normbits,
    __hip_bfloat16* __restrict__ e) {
  int i = blockIdx.x * blockDim.x + threadIdx.x;
  if (i >= N_EDGES) return;
  float norm = __uint_as_float(*normbits);
  float x = edges[i] / norm;
  float h[HID];
#pragma unroll
  for (int j = 0; j < HID; ++j) h[j] = frelu(fmaf(w1[j], x, b1[j]));
  E16 o;
#pragma unroll
  for (int j = 0; j < HID; ++j) {
    float acc = b2[j];
#pragma unroll
    for (int k = 0; k < HID; ++k) acc = fmaf(w2[j * HID + k], h[k], acc);
    o.h[j] = __float2bfloat16(acc);
  }
  float4* ep = (float4*)(e + (size_t)i * HID);
  ep[0] = o.f4[0];
  ep[1] = o.f4[1];
}

// ---------------------------------------------------------------------------
// K3: gather v3 — 2 nodes per wave (32 lanes each), 4 lanes/edge, 8 B loads.
// Now reads dense per-bucket CSR: lst = ell + off[n], deg from deg[].
// Entries are dense (no MAXDEG holes) -> fewer lines touched per node.
// Reads past deg are guarded garbage (CSR padded: PCAP - bucket_total >> 128).
// ---------------------------------------------------------------------------
__global__ __launch_bounds__(256) void k_gather(
    const unsigned short* __restrict__ e, const int* __restrict__ offp,
    const int* __restrict__ degp, const int* __restrict__ ell,
    float* __restrict__ agg) {
  int wave = (blockIdx.x * blockDim.x + threadIdx.x) >> 6;
  int lane = threadIdx.x & 63;
  int half = lane >> 5;   // which node of the pair
  int l32 = lane & 31;    // lane within node group
  int sub = l32 & 3;      // 4-channel quarter (8 B) this lane owns
  int j8 = l32 >> 2;      // edge index within a step (0..7)
  int n = wave * 2 + half;
  if (n >= N_NODES) return;  // N even; both halves always valid together
  int deg = degp[n];
  if (deg > MAXDEG) deg = MAXDEG;
  const int* lst = ell + offp[n];
  int ent0 = __builtin_nontemporal_load(lst + l32);       // slots 0..31
  int ent1 = __builtin_nontemporal_load(lst + 32 + l32);  // slots 32..63
  float as[4] = {0.f, 0.f, 0.f, 0.f};
  float ar[4] = {0.f, 0.f, 0.f, 0.f};
#pragma unroll
  for (int t = 0; t < 8; ++t) {  // slots 0..63, 8 independent loads
    int slot = t * 8 + j8;
    int entry = __shfl(t < 4 ? ent0 : ent1, half * 32 + (t & 3) * 8 + j8, 64);
    bool ok = slot < deg;
    int edge = ok ? (entry >> 1) : 0;
    ushort4 raw = *(const ushort4*)(e + (size_t)edge * HID + sub * 4);
    float v[4] = {bf2f(raw.x), bf2f(raw.y), bf2f(raw.z), bf2f(raw.w)};
    bool recv = ok && (entry & 1);
    bool send = ok && !(entry & 1);
#pragma unroll
    for (int c = 0; c < 4; ++c) {
      as[c] += send ? v[c] : 0.f;
      ar[c] += recv ? v[c] : 0.f;
    }
  }
  if (__any(deg > 64)) {  // wave-uniform; ~half of node pairs
    int ent2 = __builtin_nontemporal_load(lst + 64 + l32);
    int ent3 = __builtin_nontemporal_load(lst + 96 + l32);
#pragma unroll
    for (int t = 0; t < 8; ++t) {  // slots 64..127
      int slot = 64 + t * 8 + j8;
      int entry = __shfl(t < 4 ? ent2 : ent3, half * 32 + (t & 3) * 8 + j8, 64);
      bool ok = slot < deg;
      int edge = ok ? (entry >> 1) : 0;
      ushort4 raw = *(const ushort4*)(e + (size_t)edge * HID + sub * 4);
      float v[4] = {bf2f(raw.x), bf2f(raw.y), bf2f(raw.z), bf2f(raw.w)};
      bool recv = ok && (entry & 1);
      bool send = ok && !(entry & 1);
#pragma unroll
      for (int c = 0; c < 4; ++c) {
        as[c] += send ? v[c] : 0.f;
        ar[c] += recv ? v[c] : 0.f;
      }
    }
  }
  // reduce the 8 same-sub lanes (stride 4) within each 32-lane node group
#pragma unroll
  for (int off = 16; off >= 4; off >>= 1) {
#pragma unroll
    for (int c = 0; c < 4; ++c) {
      as[c] += __shfl_down(as[c], off, 64);
      ar[c] += __shfl_down(ar[c], off, 64);
    }
  }
  if (l32 < 4) {  // l32 == sub here
    *(float4*)(agg + (size_t)n * 32 + l32 * 4) =
        make_float4(as[0], as[1], as[2], as[3]);
    *(float4*)(agg + (size_t)n * 32 + 16 + l32 * 4) =
        make_float4(ar[0], ar[1], ar[2], ar[3]);
  }
}

// ---------------------------------------------------------------------------
// K4: node MLP (1+2H -> HID -> 1). w1 is [16][33]
// ---------------------------------------------------------------------------
__global__ __launch_bounds__(256) void k_node(
    const float* __restrict__ nodes_in, const float* __restrict__ agg,
    const float* __restrict__ w1, const float* __restrict__ b1,
    const float* __restrict__ w2, const float* __restrict__ b2,
    float* __restrict__ nodes_out) {
  int n = blockIdx.x * blockDim.x + threadIdx.x;
  if (n >= N_NODES) return;
  float x0 = nodes_in[n];
  const float4* ap = (const float4*)(agg + (size_t)n * 32);
  float av[32];
#pragma unroll
  for (int q = 0; q < 8; ++q) {
    float4 v = ap[q];
    av[q * 4 + 0] = v.x;
    av[q * 4 + 1] = v.y;
    av[q * 4 + 2] = v.z;
    av[q * 4 + 3] = v.w;
  }
  float out = b2[0];
#pragma unroll
  for (int j = 0; j < HID; ++j) {
    float acc = fmaf(w1[j * 33], x0, b1[j]);
#pragma unroll
    for (int k = 0; k < 32; ++k) acc = fmaf(w1[j * 33 + 1 + k], av[k], acc);
    out = fmaf(w2[j], frelu(acc), out);
  }
  nodes_out[n] = out;
}

// ---------------------------------------------------------------------------
// K5: edge MLP (H+2 -> HID -> HID), in-place on e (bf16 storage, fp32 math)
// ---------------------------------------------------------------------------
__global__ __launch_bounds__(256) void k_edge(
    __hip_bfloat16* __restrict__ e, const int* __restrict__ senders,
    const int* __restrict__ receivers, const float* __restrict__ nodes,
    const float* __restrict__ w1, const float* __restrict__ b1,
    const float* __restrict__ w2, const float* __restrict__ b2) {
  int i = blockIdx.x * blockDim.x + threadIdx.x;
  if (i >= N_EDGES) return;
  int s = senders[i], r = receivers[i];
  float ns = nodes[s], nr = nodes[r];
  float4* ep = (float4*)(e + (size_t)i * HID);
  E16 in;
  in.f4[0] = ep[0];
  in.f4[1] = ep[1];
  float x[HID];
#pragma unroll
  for (int k = 0; k < HID; ++k) x[k] = __bfloat162float(in.h[k]);
  float h[HID];
#pragma unroll
  for (int j = 0; j < HID; ++j) {
    float acc = b1[j];
#pragma unroll
    for (int k = 0; k < HID; ++k) acc = fmaf(w1[j * 18 + k], x[k], acc);
    acc = fmaf(w1[j * 18 + 16], ns, acc);
    acc = fmaf(w1[j * 18 + 17], nr, acc);
    h[j] = frelu(acc);
  }
  E16 o;
#pragma unroll
  for (int j = 0; j < HID; ++j) {
    float acc = b2[j];
#pragma unroll
    for (int k = 0; k < HID; ++k) acc = fmaf(w2[j * HID + k], h[k], acc);
    o.h[j] = __float2bfloat16(acc);
  }
  ep[0] = o.f4[0];
  ep[1] = o.f4[1];
}

// ---------------------------------------------------------------------------
// K6: round-3 edge MLP + decoder + out = edges + alpha*e*norm
// ---------------------------------------------------------------------------
__global__ __launch_bounds__(256) void k_final(
    const __hip_bfloat16* __restrict__ e, const int* __restrict__ senders,
    const int* __restrict__ receivers, const float* __restrict__ nodes,
    const float* __restrict__ w1, const float* __restrict__ b1,
    const float* __restrict__ w2, const float* __restrict__ b2,
    const float* __restrict__ dw1, const float* __restrict__ db1,
    const float* __restrict__ dw2, const float* __restrict__ db2,
    const float* __restrict__ edges_init,
    const unsigned int* __restrict__ normbits, const float* __restrict__ alpha,
    float* __restrict__ out) {
  int i = blockIdx.x * blockDim.x + threadIdx.x;
  if (i >= N_EDGES) return;
  int s = senders[i], r = receivers[i];
  float ns = nodes[s], nr = nodes[r];
  const float4* ep = (const float4*)(e + (size_t)i * HID);
  E16 in;
  in.f4[0] = ep[0];
  in.f4[1] = ep[1];
  float x[HID];
#pragma unroll
  for (int k = 0; k < HID; ++k) x[k] = __bfloat162float(in.h[k]);
  float h[HID];
#pragma unroll
  for (int j = 0; j < HID; ++j) {
    float acc = b1[j];
#pragma unroll
    for (int k = 0; k < HID; ++k) acc = fmaf(w1[j * 18 + k], x[k], acc);
    acc = fmaf(w1[j * 18 + 16], ns, acc);
    acc = fmaf(w1[j * 18 + 17], nr, acc);
    h[j] = frelu(acc);
  }
  float e3[HID];
#pragma unroll
  for (int j = 0; j < HID; ++j) {
    float acc = b2[j];
#pragma unroll
    for (int k = 0; k < HID; ++k) acc = fmaf(w2[j * HID + k], h[k], acc);
    e3[j] = acc;
  }
  float d = db2[0];
#pragma unroll
  for (int j = 0; j < HID; ++j) {
    float acc = db1[j];
#pragma unroll
    for (int k = 0; k < HID; ++k) acc = fmaf(dw1[j * HID + k], e3[k], acc);
    d = fmaf(dw2[j], frelu(acc), d);
  }
  float norm = __uint_as_float(*normbits);
  out[i] = fmaf(alpha[0], d * norm, edges_init[i]);
}

// ---------------------------------------------------------------------------
extern "C" void kernel_launch(void* const* d_in, const int* in_sizes, int n_in,
                              void* d_out, int out_size, void* d_ws,
                              size_t ws_size, hipStream_t stream) {
  const float* nodes0 = (const float*)d_in[0];
  const float* edges0 = (const float*)d_in[1];
  const int* senders = (const int*)d_in[2];
  const int* receivers = (const int*)d_in[3];
  const float* enc_w1 = (const float*)d_in[4];
  const float* enc_b1 = (const float*)d_in[5];
  const float* enc_w2 = (const float*)d_in[6];
  const float* enc_b2 = (const float*)d_in[7];
  const float* node_w1 = (const float*)d_in[8];
  const float* node_b1 = (const float*)d_in[9];
  const float* node_w2 = (const float*)d_in[10];
  const float* node_b2 = (const float*)d_in[11];
  const float* edge_w1 = (const float*)d_in[12];
  const float* edge_b1 = (const float*)d_in[13];
  const float* edge_w2 = (const float*)d_in[14];
  const float* edge_b2 = (const float*)d_in[15];
  const float* dec_w1 = (const float*)d_in[16];
  const float* dec_b1 = (const float*)d_in[17];
  const float* dec_w2 = (const float*)d_in[18];
  const float* dec_b2 = (const float*)d_in[19];
  const float* alpha = (const float*)d_in[20];

  // Workspace layout (~146.2 MB total; pairs aliases e, dead before k_encode):
  char* ws = (char*)d_ws;
  __hip_bfloat16* e = (__hip_bfloat16*)ws;                 // E*16 bf16 = 102.4MB
  unsigned int* pairs = (unsigned int*)ws;                 // NB*PCAP u32 = 29.4MB (alias e)
  float* agg = (float*)(ws + (size_t)N_EDGES * HID * 2);   // N*32 f32 = 12.8MB
  float* nb1 = agg + (size_t)N_NODES * 32;                 // N f32
  float* nb2 = nb1 + N_NODES;                              // N f32
  unsigned int* normbits = (unsigned int*)(nb2 + N_NODES); // 64 B slot
  int* deg = (int*)(normbits + 16);                        // N int = 0.4MB
  int* off = deg + N_NODES;                                // N int = 0.4MB
  int* gcnt = off + N_NODES;                               // NB int
  int* ell = gcnt + NB;                                    // NB*PCAP int = 29.4MB

  const int egrid = N_EDGES / BLK;  // 12500 exactly
  const int ngrid = (N_NODES + BLK - 1) / BLK;
  const int ggrid = N_NODES / 8;    // 2 nodes/wave x 4 waves/block = 12500

  hipMemsetAsync(normbits, 0, sizeof(unsigned int), stream);
  hipMemsetAsync(gcnt, 0, NB * sizeof(int), stream);
  k_norm<<<512, BLK, 0, stream>>>(edges0, normbits);
  k_split<<<256, 1024, 0, stream>>>(senders, receivers, gcnt, pairs);
  k_bsort<<<NB, 1024, 0, stream>>>(pairs, gcnt, ell, off, deg);
  k_encode<<<egrid, BLK, 0, stream>>>(edges0, enc_w1, enc_b1, enc_w2, enc_b2,
                                      normbits, e);  // overwrites pairs (dead)
  // round 1
  k_gather<<<ggrid, BLK, 0, stream>>>((const unsigned short*)e, off, deg, ell, agg);
  k_node<<<ngrid, BLK, 0, stream>>>(nodes0, agg, node_w1, node_b1, node_w2,
                                    node_b2, nb1);
  k_edge<<<egrid, BLK, 0, stream>>>(e, senders, receivers, nb1, edge_w1,
                                    edge_b1, edge_w2, edge_b2);
  // round 2
  k_gather<<<ggrid, BLK, 0, stream>>>((const unsigned short*)e, off, deg, ell, agg);
  k_node<<<ngrid, BLK, 0, stream>>>(nb1, agg, node_w1, node_b1, node_w2,
                                    node_b2, nb2);
  k_edge<<<egrid, BLK, 0, stream>>>(e, senders, receivers, nb2, edge_w1,
                                    edge_b1, edge_w2, edge_b2);
  // round 3
  k_gather<<<ggrid, BLK, 0, stream>>>((const unsigned short*)e, off, deg, ell, agg);
  k_node<<<ngrid, BLK, 0, stream>>>(nb2, agg, node_w1, node_b1, node_w2,
                                    node_b2, nb1);
  k_final<<<egrid, BLK, 0, stream>>>(e, senders, receivers, nb1, edge_w1,
                                     edge_b1, edge_w2, edge_b2, dec_w1, dec_b1,
                                     dec_w2, dec_b2, edges0, normbits, alpha,
                                     (float*)d_out);
}

// Round 2
// 872.314 us; speedup vs baseline: 1.1813x; 1.0094x over previous
//
#include <hip/hip_runtime.h>
#include <hip/hip_bf16.h>

#define N_NODES 100000
#define N_EDGES 3200000
#define HID 16
#define MAXDEG 128   // per-node entry clamp (realized max deg ~110; never fires)
#define NB 256       // node buckets for the 2-phase build
#define NPB 391      // nodes per bucket: 256*391 = 100096 >= 100000
#define PCAP 28672   // per-bucket pair capacity (mean 25024, sigma ~158 -> +23 sigma)
#define FDEPTH 48    // LDS FIFO depth per bucket in k_split
#define LCAP 26624   // LDS sort buffer entries in k_bsort (104 KB)

static constexpr int BLK = 256;

__device__ __forceinline__ float frelu(float x) { return fmaxf(x, 0.f); }
__device__ __forceinline__ float bf2f(unsigned short u) {
  return __uint_as_float(((unsigned int)u) << 16);
}
__device__ __forceinline__ float bflo(unsigned int u) {
  return __uint_as_float(u << 16);
}
__device__ __forceinline__ float bfhi(unsigned int u) {
  return __uint_as_float(u & 0xFFFF0000u);
}

// 16 bf16 (32 B) viewed as two float4 for vector load/store
union E16 {
  float4 f4[2];
  __hip_bfloat16 h[16];
};

// ---------------------------------------------------------------------------
// K0: norm = max |edges_init|
// ---------------------------------------------------------------------------
__global__ __launch_bounds__(256) void k_norm(const float* __restrict__ edges,
                                              unsigned int* __restrict__ normbits) {
  float m = 0.f;
  for (int i = blockIdx.x * blockDim.x + threadIdx.x; i < N_EDGES;
       i += gridDim.x * blockDim.x)
    m = fmaxf(m, fabsf(edges[i]));
#pragma unroll
  for (int off = 32; off > 0; off >>= 1)
    m = fmaxf(m, __shfl_down(m, off, 64));
  __shared__ float smax[BLK / 64];
  if ((threadIdx.x & 63) == 0) smax[threadIdx.x >> 6] = m;
  __syncthreads();
  if (threadIdx.x == 0) {
    float b = smax[0];
#pragma unroll
    for (int w = 1; w < BLK / 64; ++w) b = fmaxf(b, smax[w]);
    atomicMax(normbits, __float_as_uint(b));
  }
}

// ---------------------------------------------------------------------------
// K1a: multisplit edge-sides into NB node-buckets via LDS FIFOs.
// pair = (node_local << 23) | (edge << 1) | side   -- fits 32 bits (9+22+1)
// ---------------------------------------------------------------------------
__global__ __launch_bounds__(1024) void k_split(const int* __restrict__ senders,
                                                const int* __restrict__ receivers,
                                                int* __restrict__ gcnt,
                                                unsigned int* __restrict__ pairs) {
  __shared__ __align__(16) unsigned int fifo[NB][FDEPTH];
  __shared__ int fcnt[NB];
  const int t = threadIdx.x;
  if (t < NB) fcnt[t] = 0;
  __syncthreads();
  const int e0 = blockIdx.x * (N_EDGES / 256);
  const int e1 = e0 + (N_EDGES / 256);
  for (int base = e0; base < e1; base += 1024) {
    const int i = base + t;
    if (i < e1) {
      int s = senders[i];
      unsigned int bs = (unsigned int)s / NPB;
      unsigned int us = (((unsigned int)s - bs * NPB) << 23) | ((unsigned int)i << 1);
      int pos = atomicAdd(&fcnt[bs], 1);
      if (pos < FDEPTH) {
        fifo[bs][pos] = us;
      } else {  // overflow (astronomically rare): direct single append
        int gb = atomicAdd(&gcnt[bs], 1);
        if (gb < PCAP) pairs[(size_t)bs * PCAP + gb] = us;
      }
      int r = receivers[i];
      unsigned int br = (unsigned int)r / NPB;
      unsigned int ur = (((unsigned int)r - br * NPB) << 23) | ((unsigned int)i << 1) | 1u;
      pos = atomicAdd(&fcnt[br], 1);
      if (pos < FDEPTH) {
        fifo[br][pos] = ur;
      } else {
        int gb = atomicAdd(&gcnt[br], 1);
        if (gb < PCAP) pairs[(size_t)br * PCAP + gb] = ur;
      }
    }
    __syncthreads();
    const bool last = (base + 1024 >= e1);
    if (t < NB) {  // thread t owns bucket t's FIFO between barriers
      int c = fcnt[t];
      if (c > FDEPTH) c = FDEPTH;
      int nf = last ? c : (c & ~15);  // flush whole 64B lines; drain on last
      if (nf > 0) {
        int gb = atomicAdd(&gcnt[t], nf);
        unsigned int* dst = pairs + (size_t)t * PCAP + gb;
        if ((gb & 3) == 0 && gb + nf <= PCAP) {  // common case: 16B-aligned
          int k = 0;
          for (; k + 4 <= nf; k += 4)
            *(uint4*)(dst + k) = *(const uint4*)(&fifo[t][k]);
          for (; k < nf; ++k) dst[k] = fifo[t][k];
        } else {  // misaligned after a drain/overflow, or capacity edge
          for (int k = 0; k < nf; ++k)
            if (gb + k < PCAP) dst[k] = fifo[t][k];
        }
        int res = c - nf;  // res <= 15 < nf: no overlap in the memmove
        for (int k = 0; k < res; ++k) fifo[t][k] = fifo[t][nf + k];
        fcnt[t] = res;
      } else {
        fcnt[t] = c;
      }
    }
    __syncthreads();
  }
}

// ---------------------------------------------------------------------------
// K1b: per-bucket LDS counting sort -> dense per-bucket CSR (ell, off, deg).
// ---------------------------------------------------------------------------
__global__ __launch_bounds__(1024) void k_bsort(const unsigned int* __restrict__ pairs,
                                                const int* __restrict__ gcnt,
                                                int* __restrict__ ell,
                                                int* __restrict__ off,
                                                int* __restrict__ deg) {
  __shared__ unsigned int sorted[LCAP];  // 104 KB
  __shared__ int hist[NPB + 1];
  __shared__ int pref[NPB + 1];
  __shared__ int sc[NPB];
  __shared__ int cur[NPB];
  const int b = blockIdx.x;
  const int t = threadIdx.x;
  const int nt = blockDim.x;
  int nb = gcnt[b];
  if (nb > PCAP) nb = PCAP;
  const unsigned int* P = pairs + (size_t)b * PCAP;
  for (int k = t; k <= NPB; k += nt) hist[k] = 0;
  __syncthreads();
  for (int i = t; i < nb; i += nt) atomicAdd(&hist[P[i] >> 23], 1);
  __syncthreads();
  if (t < NPB) {
    int c = hist[t];
    sc[t] = (c > MAXDEG) ? MAXDEG : c;
  }
  __syncthreads();
  if (t < NPB) hist[t] = sc[t];  // keep clamped counts
  // inclusive Hillis-Steele scan of sc[0..NPB)
  for (int d = 1; d < NPB; d <<= 1) {
    int add = 0;
    if (t < NPB && t >= d) add = sc[t - d];
    __syncthreads();
    if (t < NPB && t >= d) sc[t] += add;
    __syncthreads();
  }
  if (t < NPB) pref[t] = sc[t] - hist[t];  // exclusive prefix
  if (t == 0) pref[NPB] = sc[NPB - 1];
  __syncthreads();
  // per-node CSR offsets and degrees
  const int node0 = b * NPB;
  for (int k = t; k < NPB; k += nt) {
    int n = node0 + k;
    if (n < N_NODES) {
      off[n] = b * PCAP + pref[k];
      deg[n] = hist[k];
    }
  }
  // chunked: scatter into LDS by node, then coalesced writeout
  int nlo = 0;
  while (nlo < NPB) {
    const int base0 = pref[nlo];
    int nhi = nlo;  // uniform across threads (reads shared pref)
    while (nhi < NPB && pref[nhi + 1] - base0 <= LCAP) ++nhi;
    for (int k = nlo + t; k < nhi; k += nt) cur[k] = pref[k] - base0;
    __syncthreads();
    for (int i = t; i < nb; i += nt) {
      unsigned int u = P[i];  // second read: L2-warm
      int nl = u >> 23;
      if (nl >= nlo && nl < nhi) {
        int p = atomicAdd(&cur[nl], 1);
        if (p < pref[nl] - base0 + hist[nl]) sorted[p] = u & 0x7FFFFFu;
      }
    }
    __syncthreads();
    const int csz = pref[nhi] - base0;
    int* dst = ell + (size_t)b * PCAP + base0;
    for (int i = t; i < csz; i += nt) dst[i] = (int)sorted[i];
    __syncthreads();
    nlo = nhi;
  }
}

// ---------------------------------------------------------------------------
// K2: edge encoder (1 -> HID -> HID), writes e (bf16)
// ---------------------------------------------------------------------------
__global__ __launch_bounds__(256) void k_encode(
    const float* __restrict__ edges, const float* __restrict__ w1,
    const float* __restrict__ b1, const float* __restrict__ w2,
    const float* __restrict__ b2, const unsigned int* __restrict__ normbits,
    __hip_bfloat16* __restrict__ e) {
  int i = blockIdx.x * blockDim.x + threadIdx.x;
  if (i >= N_EDGES) return;
  float norm = __uint_as_float(*normbits);
  float x = edges[i] / norm;
  float h[HID];
#pragma unroll
  for (int j = 0; j < HID; ++j) h[j] = frelu(fmaf(w1[j], x, b1[j]));
  E16 o;
#pragma unroll
  for (int j = 0; j < HID; ++j) {
    float acc = b2[j];
#pragma unroll
    for (int k = 0; k < HID; ++k) acc = fmaf(w2[j * HID + k], h[k], acc);
    o.h[j] = __float2bfloat16(acc);
  }
  float4* ep = (float4*)(e + (size_t)i * HID);
  ep[0] = o.f4[0];
  ep[1] = o.f4[1];
}

// ---------------------------------------------------------------------------
// K3: gather v4 — 2 nodes per wave (32 lanes each), now 2 lanes/edge with
// 16 B uint4 loads: 16 edges in flight per step (v3 had 8 with 8 B loads).
// Halves load-instruction count per byte and doubles scattered lines in
// flight in the latency-bound regime. Accumulation via mask-as-multiplicand
// FMA (1 cndmask/side/step instead of 2 selects+2 adds per channel).
// Entries preloaded into regs (nontemporal; CSR has zero reuse) and
// broadcast via shuffle. Stride-2 butterfly reduce, 16 B stores.
// ---------------------------------------------------------------------------
__global__ __launch_bounds__(256) void k_gather(
    const unsigned short* __restrict__ e, const int* __restrict__ offp,
    const int* __restrict__ degp, const int* __restrict__ ell,
    float* __restrict__ agg) {
  int wave = (blockIdx.x * blockDim.x + threadIdx.x) >> 6;
  int lane = threadIdx.x & 63;
  int half = lane >> 5;   // which node of the pair
  int l32 = lane & 31;    // lane within node group
  int sub = l32 & 1;      // which 16 B half (8 channels) this lane owns
  int j16 = l32 >> 1;     // edge index within a step (0..15)
  int n = wave * 2 + half;
  if (n >= N_NODES) return;  // N even; both halves always valid together
  int deg = degp[n];
  if (deg > MAXDEG) deg = MAXDEG;
  const int* lst = ell + offp[n];
  int ent0 = __builtin_nontemporal_load(lst + l32);       // slots 0..31
  int ent1 = __builtin_nontemporal_load(lst + 32 + l32);  // slots 32..63
  float as[8] = {0.f, 0.f, 0.f, 0.f, 0.f, 0.f, 0.f, 0.f};
  float ar[8] = {0.f, 0.f, 0.f, 0.f, 0.f, 0.f, 0.f, 0.f};
#pragma unroll
  for (int t = 0; t < 4; ++t) {  // slots 0..63, 16 edges per step
    int slot = t * 16 + j16;
    int entry = __shfl(t < 2 ? ent0 : ent1, half * 32 + (t & 1) * 16 + j16, 64);
    bool ok = slot < deg;
    int edge = ok ? (entry >> 1) : 0;
    uint4 raw = *(const uint4*)(e + (size_t)edge * HID + sub * 8);
    float fs = (ok && !(entry & 1)) ? 1.f : 0.f;
    float fr = (ok && (entry & 1)) ? 1.f : 0.f;
    float v[8] = {bflo(raw.x), bfhi(raw.x), bflo(raw.y), bfhi(raw.y),
                  bflo(raw.z), bfhi(raw.z), bflo(raw.w), bfhi(raw.w)};
#pragma unroll
    for (int c = 0; c < 8; ++c) {
      as[c] = fmaf(v[c], fs, as[c]);
      ar[c] = fmaf(v[c], fr, ar[c]);
    }
  }
  if (__any(deg > 64)) {  // wave-uniform; ~half of node pairs
    int ent2 = __builtin_nontemporal_load(lst + 64 + l32);
    int ent3 = __builtin_nontemporal_load(lst + 96 + l32);
#pragma unroll
    for (int t = 0; t < 4; ++t) {  // slots 64..127
      int slot = 64 + t * 16 + j16;
      int entry = __shfl(t < 2 ? ent2 : ent3, half * 32 + (t & 1) * 16 + j16, 64);
      bool ok = slot < deg;
      int edge = ok ? (entry >> 1) : 0;
      uint4 raw = *(const uint4*)(e + (size_t)edge * HID + sub * 8);
      float fs = (ok && !(entry & 1)) ? 1.f : 0.f;
      float fr = (ok && (entry & 1)) ? 1.f : 0.f;
      float v[8] = {bflo(raw.x), bfhi(raw.x), bflo(raw.y), bfhi(raw.y),
                    bflo(raw.z), bfhi(raw.z), bflo(raw.w), bfhi(raw.w)};
#pragma unroll
      for (int c = 0; c < 8; ++c) {
        as[c] = fmaf(v[c], fs, as[c]);
        ar[c] = fmaf(v[c], fr, ar[c]);
      }
    }
  }
  // reduce the 16 same-sub lanes (stride 2) within each 32-lane node group
#pragma unroll
  for (int off = 16; off >= 2; off >>= 1) {
#pragma unroll
    for (int c = 0; c < 8; ++c) {
      as[c] += __shfl_down(as[c], off, 64);
      ar[c] += __shfl_down(ar[c], off, 64);
    }
  }
  if (l32 < 2) {  // l32 == sub here; each lane owns 8 channels of as and ar
    *(float4*)(agg + (size_t)n * 32 + sub * 8) =
        make_float4(as[0], as[1], as[2], as[3]);
    *(float4*)(agg + (size_t)n * 32 + sub * 8 + 4) =
        make_float4(as[4], as[5], as[6], as[7]);
    *(float4*)(agg + (size_t)n * 32 + 16 + sub * 8) =
        make_float4(ar[0], ar[1], ar[2], ar[3]);
    *(float4*)(agg + (size_t)n * 32 + 16 + sub * 8 + 4) =
        make_float4(ar[4], ar[5], ar[6], ar[7]);
  }
}

// ---------------------------------------------------------------------------
// K4: node MLP (1+2H -> HID -> 1). w1 is [16][33]
// ---------------------------------------------------------------------------
__global__ __launch_bounds__(256) void k_node(
    const float* __restrict__ nodes_in, const float* __restrict__ agg,
    const float* __restrict__ w1, const float* __restrict__ b1,
    const float* __restrict__ w2, const float* __restrict__ b2,
    float* __restrict__ nodes_out) {
  int n = blockIdx.x * blockDim.x + threadIdx.x;
  if (n >= N_NODES) return;
  float x0 = nodes_in[n];
  const float4* ap = (const float4*)(agg + (size_t)n * 32);
  float av[32];
#pragma unroll
  for (int q = 0; q < 8; ++q) {
    float4 v = ap[q];
    av[q * 4 + 0] = v.x;
    av[q * 4 + 1] = v.y;
    av[q * 4 + 2] = v.z;
    av[q * 4 + 3] = v.w;
  }
  float out = b2[0];
#pragma unroll
  for (int j = 0; j < HID; ++j) {
    float acc = fmaf(w1[j * 33], x0, b1[j]);
#pragma unroll
    for (int k = 0; k < 32; ++k) acc = fmaf(w1[j * 33 + 1 + k], av[k], acc);
    out = fmaf(w2[j], frelu(acc), out);
  }
  nodes_out[n] = out;
}

// ---------------------------------------------------------------------------
// K5: edge MLP (H+2 -> HID -> HID), in-place on e (bf16 storage, fp32 math)
// ---------------------------------------------------------------------------
__global__ __launch_bounds__(256) void k_edge(
    __hip_bfloat16* __restrict__ e, const int* __restrict__ senders,
    const int* __restrict__ receivers, const float* __restrict__ nodes,
    const float* __restrict__ w1, const float* __restrict__ b1,
    const float* __restrict__ w2, const float* __restrict__ b2) {
  int i = blockIdx.x * blockDim.x + threadIdx.x;
  if (i >= N_EDGES) return;
  int s = senders[i], r = receivers[i];
  float ns = nodes[s], nr = nodes[r];
  float4* ep = (float4*)(e + (size_t)i * HID);
  E16 in;
  in.f4[0] = ep[0];
  in.f4[1] = ep[1];
  float x[HID];
#pragma unroll
  for (int k = 0; k < HID; ++k) x[k] = __bfloat162float(in.h[k]);
  float h[HID];
#pragma unroll
  for (int j = 0; j < HID; ++j) {
    float acc = b1[j];
#pragma unroll
    for (int k = 0; k < HID; ++k) acc = fmaf(w1[j * 18 + k], x[k], acc);
    acc = fmaf(w1[j * 18 + 16], ns, acc);
    acc = fmaf(w1[j * 18 + 17], nr, acc);
    h[j] = frelu(acc);
  }
  E16 o;
#pragma unroll
  for (int j = 0; j < HID; ++j) {
    float acc = b2[j];
#pragma unroll
    for (int k = 0; k < HID; ++k) acc = fmaf(w2[j * HID + k], h[k], acc);
    o.h[j] = __float2bfloat16(acc);
  }
  ep[0] = o.f4[0];
  ep[1] = o.f4[1];
}

// ---------------------------------------------------------------------------
// K6: round-3 edge MLP + decoder + out = edges + alpha*e*norm
// ---------------------------------------------------------------------------
__global__ __launch_bounds__(256) void k_final(
    const __hip_bfloat16* __restrict__ e, const int* __restrict__ senders,
    const int* __restrict__ receivers, const float* __restrict__ nodes,
    const float* __restrict__ w1, const float* __restrict__ b1,
    const float* __restrict__ w2, const float* __restrict__ b2,
    const float* __restrict__ dw1, const float* __restrict__ db1,
    const float* __restrict__ dw2, const float* __restrict__ db2,
    const float* __restrict__ edges_init,
    const unsigned int* __restrict__ normbits, const float* __restrict__ alpha,
    float* __restrict__ out) {
  int i = blockIdx.x * blockDim.x + threadIdx.x;
  if (i >= N_EDGES) return;
  int s = senders[i], r = receivers[i];
  float ns = nodes[s], nr = nodes[r];
  const float4* ep = (const float4*)(e + (size_t)i * HID);
  E16 in;
  in.f4[0] = ep[0];
  in.f4[1] = ep[1];
  float x[HID];
#pragma unroll
  for (int k = 0; k < HID; ++k) x[k] = __bfloat162float(in.h[k]);
  float h[HID];
#pragma unroll
  for (int j = 0; j < HID; ++j) {
    float acc = b1[j];
#pragma unroll
    for (int k = 0; k < HID; ++k) acc = fmaf(w1[j * 18 + k], x[k], acc);
    acc = fmaf(w1[j * 18 + 16], ns, acc);
    acc = fmaf(w1[j * 18 + 17], nr, acc);
    h[j] = frelu(acc);
  }
  float e3[HID];
#pragma unroll
  for (int j = 0; j < HID; ++j) {
    float acc = b2[j];
#pragma unroll
    for (int k = 0; k < HID; ++k) acc = fmaf(w2[j * HID + k], h[k], acc);
    e3[j] = acc;
  }
  float d = db2[0];
#pragma unroll
  for (int j = 0; j < HID; ++j) {
    float acc = db1[j];
#pragma unroll
    for (int k = 0; k < HID; ++k) acc = fmaf(dw1[j * HID + k], e3[k], acc);
    d = fmaf(dw2[j], frelu(acc), d);
  }
  float norm = __uint_as_float(*normbits);
  out[i] = fmaf(alpha[0], d * norm, edges_init[i]);
}

// ---------------------------------------------------------------------------
extern "C" void kernel_launch(void* const* d_in, const int* in_sizes, int n_in,
                              void* d_out, int out_size, void* d_ws,
                              size_t ws_size, hipStream_t stream) {
  const float* nodes0 = (const float*)d_in[0];
  const float* edges0 = (const float*)d_in[1];
  const int* senders = (const int*)d_in[2];
  const int* receivers = (const int*)d_in[3];
  const float* enc_w1 = (const float*)d_in[4];
  const float* enc_b1 = (const float*)d_in[5];
  const float* enc_w2 = (const float*)d_in[6];
  const float* enc_b2 = (const float*)d_in[7];
  const float* node_w1 = (const float*)d_in[8];
  const float* node_b1 = (const float*)d_in[9];
  const float* node_w2 = (const float*)d_in[10];
  const float* node_b2 = (const float*)d_in[11];
  const float* edge_w1 = (const float*)d_in[12];
  const float* edge_b1 = (const float*)d_in[13];
  const float* edge_w2 = (const float*)d_in[14];
  const float* edge_b2 = (const float*)d_in[15];
  const float* dec_w1 = (const float*)d_in[16];
  const float* dec_b1 = (const float*)d_in[17];
  const float* dec_w2 = (const float*)d_in[18];
  const float* dec_b2 = (const float*)d_in[19];
  const float* alpha = (const float*)d_in[20];

  // Workspace layout (~146.2 MB total; pairs aliases e, dead before k_encode):
  char* ws = (char*)d_ws;
  __hip_bfloat16* e = (__hip_bfloat16*)ws;                 // E*16 bf16 = 102.4MB
  unsigned int* pairs = (unsigned int*)ws;                 // NB*PCAP u32 = 29.4MB (alias e)
  float* agg = (float*)(ws + (size_t)N_EDGES * HID * 2);   // N*32 f32 = 12.8MB
  float* nb1 = agg + (size_t)N_NODES * 32;                 // N f32
  float* nb2 = nb1 + N_NODES;                              // N f32
  unsigned int* normbits = (unsigned int*)(nb2 + N_NODES); // 64 B slot
  int* deg = (int*)(normbits + 16);                        // N int = 0.4MB
  int* off = deg + N_NODES;                                // N int = 0.4MB
  int* gcnt = off + N_NODES;                               // NB int
  int* ell = gcnt + NB;                                    // NB*PCAP int = 29.4MB

  const int egrid = N_EDGES / BLK;  // 12500 exactly
  const int ngrid = (N_NODES + BLK - 1) / BLK;
  const int ggrid = N_NODES / 8;    // 2 nodes/wave x 4 waves/block = 12500

  hipMemsetAsync(normbits, 0, sizeof(unsigned int), stream);
  hipMemsetAsync(gcnt, 0, NB * sizeof(int), stream);
  k_norm<<<512, BLK, 0, stream>>>(edges0, normbits);
  k_split<<<256, 1024, 0, stream>>>(senders, receivers, gcnt, pairs);
  k_bsort<<<NB, 1024, 0, stream>>>(pairs, gcnt, ell, off, deg);
  k_encode<<<egrid, BLK, 0, stream>>>(edges0, enc_w1, enc_b1, enc_w2, enc_b2,
                                      normbits, e);  // overwrites pairs (dead)
  // round 1
  k_gather<<<ggrid, BLK, 0, stream>>>((const unsigned short*)e, off, deg, ell, agg);
  k_node<<<ngrid, BLK, 0, stream>>>(nodes0, agg, node_w1, node_b1, node_w2,
                                    node_b2, nb1);
  k_edge<<<egrid, BLK, 0, stream>>>(e, senders, receivers, nb1, edge_w1,
                                    edge_b1, edge_w2, edge_b2);
  // round 2
  k_gather<<<ggrid, BLK, 0, stream>>>((const unsigned short*)e, off, deg, ell, agg);
  k_node<<<ngrid, BLK, 0, stream>>>(nb1, agg, node_w1, node_b1, node_w2,
                                    node_b2, nb2);
  k_edge<<<egrid, BLK, 0, stream>>>(e, senders, receivers, nb2, edge_w1,
                                    edge_b1, edge_w2, edge_b2);
  // round 3
  k_gather<<<ggrid, BLK, 0, stream>>>((const unsigned short*)e, off, deg, ell, agg);
  k_node<<<ngrid, BLK, 0, stream>>>(nb2, agg, node_w1, node_b1, node_w2,
                                    node_b2, nb1);
  k_final<<<egrid, BLK, 0, stream>>>(e, senders, receivers, nb1, edge_w1,
                                     edge_b1, edge_w2, edge_b2, dec_w1, dec_b1,
                                     dec_w2, dec_b2, edges0, normbits, alpha,
                                     (float*)d_out);
}